// Round 8
// baseline (661.841 us; speedup 1.0000x reference)
//
#include <hip/hip_runtime.h>

typedef unsigned short bfraw;
typedef __attribute__((ext_vector_type(8))) short short8;
typedef __attribute__((ext_vector_type(4))) float f32x4;

__device__ __forceinline__ float b2f(bfraw u){ return __uint_as_float(((unsigned int)u)<<16); }
__device__ __forceinline__ bfraw f2b(float f){
  unsigned int u = __float_as_uint(f);
  return (bfraw)((u + 0x7FFFu + ((u>>16)&1u)) >> 16);
}
__device__ __forceinline__ void store_out(float* p, float v){ *p = v; }
__device__ __forceinline__ void store_out(bfraw* p, float v){ *p = f2b(v); }
__device__ __forceinline__ void gload_lds16(const bfraw* g, short* l) {
  __builtin_amdgcn_global_load_lds((const __attribute__((address_space(1))) void*)g,
                                   (__attribute__((address_space(3))) void*)l, 16, 0, 0);
}
// packs bf16(a) into low 16, bf16(b) into high 16 (RNE) — single VALU op
__device__ __forceinline__ unsigned int cvt_pk_bf16(float a, float b) {
  unsigned int r;
  asm("v_cvt_pk_bf16_f32 %0, %1, %2" : "=v"(r) : "v"(a), "v"(b));
  return r;
}

// ---------------- transpose + convert: out[C][R] = bf16(in[R][C]), in fp32 ------
__global__ __launch_bounds__(1024) void transpose_f32_bf16(const float* __restrict__ in,
                                                           bfraw* __restrict__ out,
                                                           int R, int C) {
  __shared__ bfraw tile[64][65];
  const int tx = threadIdx.x, ty = threadIdx.y;
  const int c0 = blockIdx.x*64, r0 = blockIdx.y*64;
  #pragma unroll
  for (int u = 0; u < 4; ++u)
    tile[ty + u*16][tx] = f2b(in[(size_t)(r0 + ty + u*16)*C + c0 + tx]);
  __syncthreads();
  #pragma unroll
  for (int u = 0; u < 4; ++u)
    out[(size_t)(c0 + ty + u*16)*R + r0 + tx] = tile[tx][ty + u*16];
}

// ---------------- layernorm over D=1024: fp32 in, fp32 params, bf16 out ----------
__global__ __launch_bounds__(256) void ln_kernel(const float* __restrict__ x,
                                                 const float* __restrict__ g,
                                                 const float* __restrict__ b,
                                                 bfraw* __restrict__ out) {
  const int row = blockIdx.x, tid = threadIdx.x;
  const f32x4 v = ((const f32x4*)(x + (size_t)row*1024))[tid];
  float s  = v[0]+v[1]+v[2]+v[3];
  float s2 = v[0]*v[0]+v[1]*v[1]+v[2]*v[2]+v[3]*v[3];
  #pragma unroll
  for (int off = 1; off < 64; off <<= 1) { s += __shfl_xor(s, off); s2 += __shfl_xor(s2, off); }
  __shared__ float red[8];
  const int wv = tid>>6, ln_ = tid&63;
  if (ln_ == 0) { red[wv] = s; red[4+wv] = s2; }
  __syncthreads();
  float a  = red[0]+red[1]+red[2]+red[3];
  float a2 = red[4]+red[5]+red[6]+red[7];
  float mean = a*(1.0f/1024.0f);
  float var  = a2*(1.0f/1024.0f) - mean*mean;
  float inv  = rsqrtf(var + 1e-5f);
  const f32x4 gr = ((const f32x4*)g)[tid];
  const f32x4 br = ((const f32x4*)b)[tid];
  ushort4 o4;
  o4.x = f2b((v[0]-mean)*inv*gr[0] + br[0]);
  o4.y = f2b((v[1]-mean)*inv*gr[1] + br[1]);
  o4.z = f2b((v[2]-mean)*inv*gr[2] + br[2]);
  o4.w = f2b((v[3]-mean)*inv*gr[3] + br[3]);
  ((ushort4*)(out + (size_t)row*1024))[tid] = o4;
}

// ---------------- GEMM: C[M,N] = A[M,K] * Bt[N,K]^T (+epilogue) -------------------
// R1-proven m97 structure (128^2 tile, 32KB LDS, ~3 blocks/CU cross-block overlap).
// 2D grid exactly as R1 (bn-fast 1D swizzle measured -8us in R6; reverted).
// EPI: 0 = none, 1 = +bias +resid, 2 = +bias +exact GELU
template<int EPI, typename OutT>
__global__ __launch_bounds__(256) void gemm_bt(const bfraw* __restrict__ A,
                                               const bfraw* __restrict__ Bt,
                                               const float* __restrict__ bias,
                                               const float* __restrict__ resid,
                                               OutT* __restrict__ C,
                                               int M, int N, int K) {
  __shared__ __align__(16) short As[128*32];
  __shared__ __align__(16) short Bs[128*32];
  const int tid = threadIdx.x;
  const int wave = tid>>6, lane = tid&63;
  const int wm = wave>>1, wn = wave&1;
  const int q = lane>>4, r = lane&15;
  const int bm = blockIdx.x, bn = blockIdx.y;

  const int m0 = tid>>2, c0 = tid&3;
  const bfraw* Ag0 = A  + (size_t)(bm*128      + m0)*K + c0*8;
  const bfraw* Ag1 = A  + (size_t)(bm*128 + 64 + m0)*K + c0*8;
  const bfraw* Bg0 = Bt + (size_t)(bn*128      + m0)*K + c0*8;
  const bfraw* Bg1 = Bt + (size_t)(bn*128 + 64 + m0)*K + c0*8;
  short* Al0 = &As[tid*8];
  short* Al1 = &As[(256+tid)*8];
  short* Bl0 = &Bs[tid*8];
  short* Bl1 = &Bs[(256+tid)*8];

  f32x4 acc[4][4];
  #pragma unroll
  for (int mi = 0; mi < 4; ++mi)
    #pragma unroll
    for (int ni = 0; ni < 4; ++ni)
      acc[mi][ni] = (f32x4){0.f, 0.f, 0.f, 0.f};

  for (int k0 = 0; k0 < K; k0 += 32) {
    __syncthreads();               // protect LDS readers of previous tile
    gload_lds16(Ag0 + k0, Al0);
    gload_lds16(Ag1 + k0, Al1);
    gload_lds16(Bg0 + k0, Bl0);
    gload_lds16(Bg1 + k0, Bl1);
    __syncthreads();               // vmcnt drained by compiler before barrier
    short8 af[4], bfr[4];
    #pragma unroll
    for (int mi = 0; mi < 4; ++mi)
      af[mi] = *(const short8*)&As[(wm*64 + mi*16 + r)*32 + q*8];
    #pragma unroll
    for (int ni = 0; ni < 4; ++ni)
      bfr[ni] = *(const short8*)&Bs[(wn*64 + ni*16 + r)*32 + q*8];
    #pragma unroll
    for (int mi = 0; mi < 4; ++mi)
      #pragma unroll
      for (int ni = 0; ni < 4; ++ni)
        acc[mi][ni] = __builtin_amdgcn_mfma_f32_16x16x32_bf16(af[mi], bfr[ni], acc[mi][ni], 0, 0, 0);
  }

  #pragma unroll
  for (int mi = 0; mi < 4; ++mi) {
    #pragma unroll
    for (int ni = 0; ni < 4; ++ni) {
      const int gcol = bn*128 + wn*64 + ni*16 + r;
      float bv = 0.f;
      if constexpr (EPI != 0) bv = bias[gcol];
      #pragma unroll
      for (int rg = 0; rg < 4; ++rg) {
        const int grow = bm*128 + wm*64 + mi*16 + q*4 + rg;
        float val = acc[mi][ni][rg];
        if constexpr (EPI != 0) val += bv;
        if constexpr (EPI == 2) val = 0.5f*val*(1.0f + erff(val*0.70710678118654752f));
        if constexpr (EPI == 1) val += resid[(size_t)grow*N + gcol];
        store_out(&C[(size_t)grow*N + gcol], val);
      }
    }
  }
}

// ---------------- MFMA flash attention (causal), T=2048, HD=64, scale=1/8 ---------
// v4: KVBLK=128 (uniform 17 chunks/block with diagonal pairing), double-buffered
// K/V LDS, ONE barrier per chunk (lgkmcnt(0)+s_barrier, NO vmcnt drain -> the
// 2-chunk-ahead global prefetch stays in flight across barriers). All LDS swizzles
// rebuilt so both write AND read sides spread across all 8 16B windows per instr
// (read-side keys: K chunk ^ (key&7)=r&7; V pos ^ (d&7) ^ ((d>>3)&7); P ^ (r&7)).
// S^T orientation / scalar softmax state / cvt_pk P-pack kept from R1.
__global__ __launch_bounds__(256) void flash_attn(const bfraw* __restrict__ qkv,
                                                  bfraw* __restrict__ o) {
  __shared__ __align__(16) short Ksh[2][8192];   // [buf][128 keys][64 dims]
  __shared__ __align__(16) short Vts[2][8192];   // [buf][64 dims][128 keys]
  __shared__ __align__(16) short Psh[4][2048];   // per wave [16 q-rows][128 keys]
  const int tid = threadIdx.x;
  const int w = tid >> 6, lane = tid & 63;
  const int r = lane & 15, qd = lane >> 4;
  const int bb = blockIdx.y >> 4, h = blockIdx.y & 15;
  const size_t hb = (size_t)bb * 2048;
  short* Pw = &Psh[w][0];
  // staging geometry: thread covers chunks c = i*256+tid, i=0..3:
  //   key = 32*i + (tid>>3), dim-col = (tid&7)*8
  const int skey = tid >> 3, sa = tid & 7, sdc = sa * 8, sk7 = skey & 7;
  const int kposz = ((sa ^ sk7) & 7) << 3;       // K store position (shorts)

  short8 kpre[4], vpre[4];

  for (int pass = 0; pass < 2; ++pass) {
    const int qt = pass ? (31 - (int)blockIdx.x) : (int)blockIdx.x;
    const int q0 = qt * 64;
    const int nchunk = (qt >> 1) + 1;

    // Q fragments: lane holds Q[q=r][k=qd*8+ks*32+j] (B operand)
    short8 qf[2];
    {
      const bfraw* qrow = qkv + (hb + q0 + w*16 + r) * 3072 + h*64;
      qf[0] = *(const short8*)(qrow + qd*8);
      qf[1] = *(const short8*)(qrow + qd*8 + 32);
    }

    f32x4 oacc[4];
    #pragma unroll
    for (int nt = 0; nt < 4; ++nt) oacc[nt] = (f32x4){0.f,0.f,0.f,0.f};
    float m_i = -3.0e38f;
    float l_i = 0.f;

    // ---- prologue: chunk 0 -> regs -> buf0; prefetch chunk 1 ----
    {
      const bfraw* p0 = qkv + (hb + skey) * 3072 + h*64 + sdc;
      #pragma unroll
      for (int i = 0; i < 4; ++i) {
        const bfraw* p = p0 + (size_t)i*32*3072;
        kpre[i] = *(const short8*)(p + 1024);
        vpre[i] = *(const short8*)(p + 2048);
      }
    }
    __syncthreads();   // previous pass's readers done before restage
    #pragma unroll
    for (int i = 0; i < 4; ++i) {
      *(short8*)&Ksh[0][(32*i + skey)*64 + kposz] = kpre[i];
      const int kg = 4*i + w;
      #pragma unroll
      for (int j = 0; j < 8; ++j)
        Vts[0][(sdc + j)*128 + (((kg & 8) | ((kg ^ j ^ sa) & 7)) << 3) + sk7] = vpre[i][j];
    }
    if (nchunk > 1) {
      const bfraw* p0 = qkv + (hb + 128 + skey) * 3072 + h*64 + sdc;
      #pragma unroll
      for (int i = 0; i < 4; ++i) {
        const bfraw* p = p0 + (size_t)i*32*3072;
        kpre[i] = *(const short8*)(p + 1024);
        vpre[i] = *(const short8*)(p + 2048);
      }
    }
    asm volatile("s_waitcnt lgkmcnt(0)" ::: "memory");
    __builtin_amdgcn_s_barrier();

    for (int t = 0; t < nchunk; ++t) {
      const int buf = t & 1;
      // ---- stage chunk t+1 (from prefetched regs) into the other buffer ----
      if (t + 1 < nchunk) {
        const int nb = buf ^ 1;
        #pragma unroll
        for (int i = 0; i < 4; ++i) {
          *(short8*)&Ksh[nb][(32*i + skey)*64 + kposz] = kpre[i];
          const int kg = 4*i + w;
          #pragma unroll
          for (int j = 0; j < 8; ++j)
            Vts[nb][(sdc + j)*128 + (((kg & 8) | ((kg ^ j ^ sa) & 7)) << 3) + sk7] = vpre[i][j];
        }
      }
      // ---- prefetch chunk t+2 into regs (in flight across the barrier) ----
      if (t + 2 < nchunk) {
        const bfraw* p0 = qkv + (hb + (t+2)*128 + skey) * 3072 + h*64 + sdc;
        #pragma unroll
        for (int i = 0; i < 4; ++i) {
          const bfraw* p = p0 + (size_t)i*32*3072;
          kpre[i] = *(const short8*)(p + 1024);
          vpre[i] = *(const short8*)(p + 2048);
        }
      }

      // ---- S^T = K Q^T : 8 key-tiles x 2 k-steps ----
      const short* Kb = &Ksh[buf][0];
      const short* Vb = &Vts[buf][0];
      f32x4 s4[8];
      __builtin_amdgcn_s_setprio(1);
      #pragma unroll
      for (int kt = 0; kt < 8; ++kt) {
        f32x4 a = (f32x4){0.f,0.f,0.f,0.f};
        const int key = kt*16 + r;
        #pragma unroll
        for (int ks = 0; ks < 2; ++ks) {
          short8 kf8 = *(const short8*)&Kb[key*64 + ((((qd + ks*4) ^ (r & 7)) & 7) << 3)];
          a = __builtin_amdgcn_mfma_f32_16x16x32_bf16(kf8, qf[ks], a, 0, 0, 0);
        }
        s4[kt] = a;
      }
      __builtin_amdgcn_s_setprio(0);

      // ---- scale + causal mask (last chunk only) ----
      const bool diag = (t == nchunk - 1);
      const int dqr = q0 + w*16 + r - t*128;   // qrow - key-base
      #pragma unroll
      for (int kt = 0; kt < 8; ++kt)
        #pragma unroll
        for (int rg = 0; rg < 4; ++rg) {
          float v = s4[kt][rg] * 0.125f;
          if (diag && (kt*16 + qd*4 + rg > dqr)) v = -3.0e38f;
          s4[kt][rg] = v;
        }

      // ---- online softmax (one rescale per 128 keys) ----
      float mx = s4[0][0];
      #pragma unroll
      for (int kt = 0; kt < 8; ++kt)
        #pragma unroll
        for (int rg = 0; rg < 4; ++rg) mx = fmaxf(mx, s4[kt][rg]);
      mx = fmaxf(mx, __shfl_xor(mx, 16));
      mx = fmaxf(mx, __shfl_xor(mx, 32));
      const float mn = fmaxf(m_i, mx);
      const float alpha = __expf(m_i - mn);
      m_i = mn;
      l_i *= alpha;

      float lsum = 0.f;
      #pragma unroll
      for (int kt = 0; kt < 8; ++kt) {
        const float p0 = __expf(s4[kt][0] - mn);
        const float p1 = __expf(s4[kt][1] - mn);
        const float p2 = __expf(s4[kt][2] - mn);
        const float p3 = __expf(s4[kt][3] - mn);
        lsum += (p0 + p1) + (p2 + p3);
        uint2 pk;
        pk.x = cvt_pk_bf16(p0, p1);
        pk.y = cvt_pk_bf16(p2, p3);
        const int c = 2*kt + (qd >> 1);
        const int pos = (c & 8) | ((c ^ (r & 7)) & 7);
        *(uint2*)((char*)Pw + r*256 + (pos << 4) + ((qd & 1) << 3)) = pk;
      }
      lsum += __shfl_xor(lsum, 16);
      lsum += __shfl_xor(lsum, 32);
      l_i += lsum;
      #pragma unroll
      for (int nt = 0; nt < 4; ++nt)
        #pragma unroll
        for (int rg = 0; rg < 4; ++rg) oacc[nt][rg] *= alpha;

      // ---- O^T += Vt Pt : 4 d-tiles x 4 k-steps ----
      short8 pf[4];
      #pragma unroll
      for (int ks = 0; ks < 4; ++ks) {
        const int c = 4*ks + qd;
        const int pos = (c & 8) | ((c ^ (r & 7)) & 7);
        pf[ks] = *(const short8*)&Pw[r*128 + (pos << 3)];
      }
      __builtin_amdgcn_s_setprio(1);
      #pragma unroll
      for (int nt = 0; nt < 4; ++nt) {
        const int d = nt*16 + r;
        const int dx = (r & 7) ^ ((d >> 3) & 7);
        #pragma unroll
        for (int ks = 0; ks < 4; ++ks) {
          const int c = qd + 4*ks;
          const int pos = (c & 8) | ((c ^ dx) & 7);
          short8 vf = *(const short8*)&Vb[d*128 + (pos << 3)];
          oacc[nt] = __builtin_amdgcn_mfma_f32_16x16x32_bf16(vf, pf[ks], oacc[nt], 0, 0, 0);
        }
      }
      __builtin_amdgcn_s_setprio(0);

      // ---- single barrier per chunk: publish LDS, keep vmcnt in flight ----
      asm volatile("s_waitcnt lgkmcnt(0)" ::: "memory");
      __builtin_amdgcn_s_barrier();
    }

    // epilogue: O[q=r][d = nt*16 + qd*4 + rg], lane-local scale, 8B vector stores
    const float invl = 1.0f / l_i;
    bfraw* orow = o + (hb + q0 + w*16 + r) * 1024 + h*64;
    #pragma unroll
    for (int nt = 0; nt < 4; ++nt) {
      uint2 ov;
      ov.x = cvt_pk_bf16(oacc[nt][0]*invl, oacc[nt][1]*invl);
      ov.y = cvt_pk_bf16(oacc[nt][2]*invl, oacc[nt][3]*invl);
      *(uint2*)(orow + nt*16 + qd*4) = ov;
    }
  }
}

// ---------------- host ----------------
extern "C" void kernel_launch(void* const* d_in, const int* in_sizes, int n_in,
                              void* d_out, int out_size, void* d_ws, size_t ws_size,
                              hipStream_t stream) {
  (void)in_sizes; (void)n_in;
  const float* x    = (const float*)d_in[0];
  // d_in[1] = causal mask (int32) -- deterministic tril, handled analytically
  const float* ln1g = (const float*)d_in[2];
  const float* ln1b = (const float*)d_in[3];
  const float* ln2g = (const float*)d_in[4];
  const float* ln2b = (const float*)d_in[5];
  const float* qkvw = (const float*)d_in[6];
  const float* outw = (const float*)d_in[7];
  const float* outb = (const float*)d_in[8];
  const float* fc1w = (const float*)d_in[9];
  const float* fc1b = (const float*)d_in[10];
  const float* fc2w = (const float*)d_in[11];
  const float* fc2b = (const float*)d_in[12];
  float* out = (float*)d_out;   // reference output dtype = float32

  char* ws = (char*)d_ws;
  size_t off = 0;
  auto alloc = [&](size_t bytes) -> void* { void* p = ws + off; off += (bytes + 255) & ~(size_t)255; return p; };
  bfraw* wt_qkv = (bfraw*)alloc(3072ULL*1024*2);
  bfraw* wt_out = (bfraw*)alloc(1024ULL*1024*2);
  bfraw* wt_fc1 = (bfraw*)alloc(4096ULL*1024*2);
  bfraw* wt_fc2 = (bfraw*)alloc(1024ULL*4096*2);
  bfraw* hbuf   = (bfraw*)alloc(8192ULL*1024*2);
  float* x1     = (float*)alloc(8192ULL*1024*4);
  char*  big    = (char*) alloc(8192ULL*3072*2 + 8192ULL*1024*2);
  bfraw* qkv  = (bfraw*)big;
  bfraw* obuf = (bfraw*)(big + 8192ULL*3072*2);
  bfraw* hf   = (bfraw*)big;

  if (off > ws_size) {
    (void)hipMemsetAsync(d_out, 0x7F, (size_t)out_size*4, stream);
    return;
  }

  dim3 tb(64, 16);
  transpose_f32_bf16<<<dim3(48, 16), tb, 0, stream>>>(qkvw, wt_qkv, 1024, 3072);
  transpose_f32_bf16<<<dim3(16, 16), tb, 0, stream>>>(outw, wt_out, 1024, 1024);
  transpose_f32_bf16<<<dim3(64, 16), tb, 0, stream>>>(fc1w, wt_fc1, 1024, 4096);
  transpose_f32_bf16<<<dim3(16, 64), tb, 0, stream>>>(fc2w, wt_fc2, 4096, 1024);

  ln_kernel<<<8192, 256, 0, stream>>>(x, ln1g, ln1b, hbuf);
  gemm_bt<0, bfraw><<<dim3(64, 24), 256, 0, stream>>>(hbuf, wt_qkv, nullptr, nullptr, qkv, 8192, 3072, 1024);
  flash_attn<<<dim3(16, 64), 256, 0, stream>>>(qkv, obuf);
  gemm_bt<1, float><<<dim3(64, 8), 256, 0, stream>>>(obuf, wt_out, outb, x, x1, 8192, 1024, 1024);
  ln_kernel<<<8192, 256, 0, stream>>>(x1, ln2g, ln2b, hbuf);
  gemm_bt<2, bfraw><<<dim3(64, 32), 256, 0, stream>>>(hbuf, wt_fc1, fc1b, nullptr, hf, 8192, 4096, 1024);
  gemm_bt<1, float><<<dim3(64, 8), 256, 0, stream>>>(hf, wt_fc2, fc2b, x1, out, 8192, 1024, 4096);
}

// Round 9
// 602.537 us; speedup vs baseline: 1.0984x; 1.0984x over previous
//
#include <hip/hip_runtime.h>

typedef unsigned short bfraw;
typedef __attribute__((ext_vector_type(8))) short short8;
typedef __attribute__((ext_vector_type(4))) float f32x4;

__device__ __forceinline__ float b2f(bfraw u){ return __uint_as_float(((unsigned int)u)<<16); }
__device__ __forceinline__ bfraw f2b(float f){
  unsigned int u = __float_as_uint(f);
  return (bfraw)((u + 0x7FFFu + ((u>>16)&1u)) >> 16);
}
__device__ __forceinline__ void store_out(float* p, float v){ *p = v; }
__device__ __forceinline__ void store_out(bfraw* p, float v){ *p = f2b(v); }
__device__ __forceinline__ void gload_lds16(const bfraw* g, short* l) {
  __builtin_amdgcn_global_load_lds((const __attribute__((address_space(1))) void*)g,
                                   (__attribute__((address_space(3))) void*)l, 16, 0, 0);
}
// packs bf16(a) into low 16, bf16(b) into high 16 (RNE) — single VALU op
__device__ __forceinline__ unsigned int cvt_pk_bf16(float a, float b) {
  unsigned int r;
  asm("v_cvt_pk_bf16_f32 %0, %1, %2" : "=v"(r) : "v"(a), "v"(b));
  return r;
}

// ---------------- transpose + convert: out[C][R] = bf16(in[R][C]), in fp32 ------
__global__ __launch_bounds__(1024) void transpose_f32_bf16(const float* __restrict__ in,
                                                           bfraw* __restrict__ out,
                                                           int R, int C) {
  __shared__ bfraw tile[64][65];
  const int tx = threadIdx.x, ty = threadIdx.y;
  const int c0 = blockIdx.x*64, r0 = blockIdx.y*64;
  #pragma unroll
  for (int u = 0; u < 4; ++u)
    tile[ty + u*16][tx] = f2b(in[(size_t)(r0 + ty + u*16)*C + c0 + tx]);
  __syncthreads();
  #pragma unroll
  for (int u = 0; u < 4; ++u)
    out[(size_t)(c0 + ty + u*16)*R + r0 + tx] = tile[tx][ty + u*16];
}

// ---------------- layernorm over D=1024: fp32 in, fp32 params, bf16 out ----------
__global__ __launch_bounds__(256) void ln_kernel(const float* __restrict__ x,
                                                 const float* __restrict__ g,
                                                 const float* __restrict__ b,
                                                 bfraw* __restrict__ out) {
  const int row = blockIdx.x, tid = threadIdx.x;
  const f32x4 v = ((const f32x4*)(x + (size_t)row*1024))[tid];
  float s  = v[0]+v[1]+v[2]+v[3];
  float s2 = v[0]*v[0]+v[1]*v[1]+v[2]*v[2]+v[3]*v[3];
  #pragma unroll
  for (int off = 1; off < 64; off <<= 1) { s += __shfl_xor(s, off); s2 += __shfl_xor(s2, off); }
  __shared__ float red[8];
  const int wv = tid>>6, ln_ = tid&63;
  if (ln_ == 0) { red[wv] = s; red[4+wv] = s2; }
  __syncthreads();
  float a  = red[0]+red[1]+red[2]+red[3];
  float a2 = red[4]+red[5]+red[6]+red[7];
  float mean = a*(1.0f/1024.0f);
  float var  = a2*(1.0f/1024.0f) - mean*mean;
  float inv  = rsqrtf(var + 1e-5f);
  const f32x4 gr = ((const f32x4*)g)[tid];
  const f32x4 br = ((const f32x4*)b)[tid];
  ushort4 o4;
  o4.x = f2b((v[0]-mean)*inv*gr[0] + br[0]);
  o4.y = f2b((v[1]-mean)*inv*gr[1] + br[1]);
  o4.z = f2b((v[2]-mean)*inv*gr[2] + br[2]);
  o4.w = f2b((v[3]-mean)*inv*gr[3] + br[3]);
  ((ushort4*)(out + (size_t)row*1024))[tid] = o4;
}

// ---------------- GEMM: C[M,N] = A[M,K] * Bt[N,K]^T (+epilogue) -------------------
// R1-proven m97 structure (128^2 tile, 32KB LDS, ~3 blocks/CU cross-block overlap).
// 2D grid exactly as R1. EPI: 0 = none, 1 = +bias +resid, 2 = +bias +exact GELU
template<int EPI, typename OutT>
__global__ __launch_bounds__(256) void gemm_bt(const bfraw* __restrict__ A,
                                               const bfraw* __restrict__ Bt,
                                               const float* __restrict__ bias,
                                               const float* __restrict__ resid,
                                               OutT* __restrict__ C,
                                               int M, int N, int K) {
  __shared__ __align__(16) short As[128*32];
  __shared__ __align__(16) short Bs[128*32];
  const int tid = threadIdx.x;
  const int wave = tid>>6, lane = tid&63;
  const int wm = wave>>1, wn = wave&1;
  const int q = lane>>4, r = lane&15;
  const int bm = blockIdx.x, bn = blockIdx.y;

  const int m0 = tid>>2, c0 = tid&3;
  const bfraw* Ag0 = A  + (size_t)(bm*128      + m0)*K + c0*8;
  const bfraw* Ag1 = A  + (size_t)(bm*128 + 64 + m0)*K + c0*8;
  const bfraw* Bg0 = Bt + (size_t)(bn*128      + m0)*K + c0*8;
  const bfraw* Bg1 = Bt + (size_t)(bn*128 + 64 + m0)*K + c0*8;
  short* Al0 = &As[tid*8];
  short* Al1 = &As[(256+tid)*8];
  short* Bl0 = &Bs[tid*8];
  short* Bl1 = &Bs[(256+tid)*8];

  f32x4 acc[4][4];
  #pragma unroll
  for (int mi = 0; mi < 4; ++mi)
    #pragma unroll
    for (int ni = 0; ni < 4; ++ni)
      acc[mi][ni] = (f32x4){0.f, 0.f, 0.f, 0.f};

  for (int k0 = 0; k0 < K; k0 += 32) {
    __syncthreads();               // protect LDS readers of previous tile
    gload_lds16(Ag0 + k0, Al0);
    gload_lds16(Ag1 + k0, Al1);
    gload_lds16(Bg0 + k0, Bl0);
    gload_lds16(Bg1 + k0, Bl1);
    __syncthreads();               // vmcnt drained by compiler before barrier
    short8 af[4], bfr[4];
    #pragma unroll
    for (int mi = 0; mi < 4; ++mi)
      af[mi] = *(const short8*)&As[(wm*64 + mi*16 + r)*32 + q*8];
    #pragma unroll
    for (int ni = 0; ni < 4; ++ni)
      bfr[ni] = *(const short8*)&Bs[(wn*64 + ni*16 + r)*32 + q*8];
    #pragma unroll
    for (int mi = 0; mi < 4; ++mi)
      #pragma unroll
      for (int ni = 0; ni < 4; ++ni)
        acc[mi][ni] = __builtin_amdgcn_mfma_f32_16x16x32_bf16(af[mi], bfr[ni], acc[mi][ni], 0, 0, 0);
  }

  #pragma unroll
  for (int mi = 0; mi < 4; ++mi) {
    #pragma unroll
    for (int ni = 0; ni < 4; ++ni) {
      const int gcol = bn*128 + wn*64 + ni*16 + r;
      float bv = 0.f;
      if constexpr (EPI != 0) bv = bias[gcol];
      #pragma unroll
      for (int rg = 0; rg < 4; ++rg) {
        const int grow = bm*128 + wm*64 + mi*16 + q*4 + rg;
        float val = acc[mi][ni][rg];
        if constexpr (EPI != 0) val += bv;
        if constexpr (EPI == 2) val = 0.5f*val*(1.0f + erff(val*0.70710678118654752f));
        if constexpr (EPI == 1) val += resid[(size_t)grow*N + gcol];
        store_out(&C[(size_t)grow*N + gcol], val);
      }
    }
  }
}

// ---------------- MFMA flash attention (causal), T=2048, HD=64, scale=1/8 ---------
// v5 = R1 + double-buffered K/V only. Everything else byte-identical to R1
// (KVBLK=64, R1 swizzles, kpre/vpre[2] register prefetch, S^T orientation,
// scalar softmax, cvt_pk P-pack). Change: K/V LDS is [2][4096] (40 KiB total,
// still 4 blocks/CU = grid-imposed residency) and the tile loop has ONE
// lgkmcnt(0)+s_barrier per tile instead of two __syncthreads:
//   iter t: write buf[cur^1] (its readers finished before end-of-(t-1) barrier:
//   ds_read data is consumed by MFMAs before the barrier), prefetch t+2 (stays
//   in flight across the barrier - no vmcnt drain), compute from buf[cur]
//   (published by end-of-(t-1) barrier), then lgkmcnt(0)+s_barrier.
__global__ __launch_bounds__(256) void flash_attn(const bfraw* __restrict__ qkv,
                                                  bfraw* __restrict__ o) {
  __shared__ __align__(16) short Ksh[2][4096];
  __shared__ __align__(16) short Vts[2][4096];
  __shared__ __align__(16) short Psh[4096];
  const int tid = threadIdx.x;
  const int w = tid >> 6, lane = tid & 63;
  const int r = lane & 15, qd = lane >> 4;
  const int bb = blockIdx.y >> 4, h = blockIdx.y & 15;
  const size_t hb = (size_t)bb * 2048;
  short* Pw = &Psh[w * 1024];
  const int f0 = tid, f1 = tid + 256;
  const int key0 = f0 >> 3, dc0 = (f0 & 7) * 8;
  const int key1 = f1 >> 3, dc1 = (f1 & 7) * 8;

  short8 kpre[2], vpre[2];

  for (int pass = 0; pass < 2; ++pass) {
    const int qt = pass ? (31 - (int)blockIdx.x) : (int)blockIdx.x;
    const int q0 = qt * 64;
    const int ntile = qt + 1;

    // Q fragments: lane holds Q[q=r][k=qd*8+ks*32+j] (B operand)
    short8 qf[2];
    {
      const bfraw* qrow = qkv + (hb + q0 + w*16 + r) * 3072 + h*64;
      qf[0] = *(const short8*)(qrow + qd*8);
      qf[1] = *(const short8*)(qrow + qd*8 + 32);
    }

    f32x4 oacc[4];
    #pragma unroll
    for (int nt = 0; nt < 4; ++nt) oacc[nt] = (f32x4){0.f,0.f,0.f,0.f};
    float m_i = -3.0e38f;
    float l_i = 0.f;

    // ---- prologue: tile 0 -> regs -> buf0; prefetch tile 1 ----
    {
      const bfraw* b0 = qkv + (hb + key0) * 3072 + h*64 + dc0;
      const bfraw* b1 = qkv + (hb + key1) * 3072 + h*64 + dc1;
      kpre[0] = *(const short8*)(b0 + 1024); vpre[0] = *(const short8*)(b0 + 2048);
      kpre[1] = *(const short8*)(b1 + 1024); vpre[1] = *(const short8*)(b1 + 2048);
    }
    __syncthreads();   // previous pass's readers done before restaging buf0
    #pragma unroll
    for (int pz = 0; pz < 2; ++pz) {
      const int key = pz ? key1 : key0, dc = pz ? dc1 : dc0;
      *(short8*)&Ksh[0][key*64 + ((((dc>>3) ^ (key>>3)) & 7) << 3)] = kpre[pz];
      const int kg = key >> 3, k7 = key & 7, dg = dc >> 3;
      #pragma unroll
      for (int i2 = 0; i2 < 8; ++i2)
        Vts[0][(dc + i2)*64 + (((kg ^ dg) & 7) << 3) + k7] = vpre[pz][i2];
    }
    if (ntile > 1) {
      const bfraw* b0 = qkv + (hb + 64 + key0) * 3072 + h*64 + dc0;
      const bfraw* b1 = qkv + (hb + 64 + key1) * 3072 + h*64 + dc1;
      kpre[0] = *(const short8*)(b0 + 1024); vpre[0] = *(const short8*)(b0 + 2048);
      kpre[1] = *(const short8*)(b1 + 1024); vpre[1] = *(const short8*)(b1 + 2048);
    }
    asm volatile("s_waitcnt lgkmcnt(0)" ::: "memory");
    __builtin_amdgcn_s_barrier();

    for (int t = 0; t < ntile; ++t) {
      const int cur = t & 1;
      // ---- stage tile t+1 (prefetched regs) into the other buffer ----
      if (t + 1 < ntile) {
        const int nb = cur ^ 1;
        #pragma unroll
        for (int pz = 0; pz < 2; ++pz) {
          const int key = pz ? key1 : key0, dc = pz ? dc1 : dc0;
          *(short8*)&Ksh[nb][key*64 + ((((dc>>3) ^ (key>>3)) & 7) << 3)] = kpre[pz];
          const int kg = key >> 3, k7 = key & 7, dg = dc >> 3;
          #pragma unroll
          for (int i2 = 0; i2 < 8; ++i2)
            Vts[nb][(dc + i2)*64 + (((kg ^ dg) & 7) << 3) + k7] = vpre[pz][i2];
        }
      }
      // ---- prefetch tile t+2 into regs (in flight across the barrier) ----
      if (t + 2 < ntile) {
        const int j0n = (t + 2) * 64;
        const bfraw* b0 = qkv + (hb + j0n + key0) * 3072 + h*64 + dc0;
        const bfraw* b1 = qkv + (hb + j0n + key1) * 3072 + h*64 + dc1;
        kpre[0] = *(const short8*)(b0 + 1024); vpre[0] = *(const short8*)(b0 + 2048);
        kpre[1] = *(const short8*)(b1 + 1024); vpre[1] = *(const short8*)(b1 + 2048);
      }

      // ---- S^T = K Q^T : col = lane&15 = q-row, row = kt*16 + qd*4 + rg = key ----
      const short* Kb = &Ksh[cur][0];
      const short* Vb = &Vts[cur][0];
      f32x4 s4[4];
      __builtin_amdgcn_s_setprio(1);
      #pragma unroll
      for (int kt = 0; kt < 4; ++kt) {
        f32x4 a = (f32x4){0.f,0.f,0.f,0.f};
        const int key = kt*16 + r, kgk = key >> 3;
        #pragma unroll
        for (int ks = 0; ks < 2; ++ks) {
          short8 kf8 = *(const short8*)&Kb[key*64 + ((((qd + ks*4) ^ kgk) & 7) << 3)];
          a = __builtin_amdgcn_mfma_f32_16x16x32_bf16(kf8, qf[ks], a, 0, 0, 0);
        }
        s4[kt] = a;
      }
      __builtin_amdgcn_s_setprio(0);

      // ---- scale + causal mask (diagonal tile only) ----
      const bool diag = (t == qt);
      #pragma unroll
      for (int kt = 0; kt < 4; ++kt)
        #pragma unroll
        for (int rg = 0; rg < 4; ++rg) {
          float v = s4[kt][rg] * 0.125f;
          if (diag && (kt*16 + qd*4 + rg > w*16 + r)) v = -3.0e38f;
          s4[kt][rg] = v;
        }

      // ---- online softmax: lane owns row r; 16 keys + xor(16,32) reduce ----
      float mx = s4[0][0];
      #pragma unroll
      for (int kt = 0; kt < 4; ++kt)
        #pragma unroll
        for (int rg = 0; rg < 4; ++rg) mx = fmaxf(mx, s4[kt][rg]);
      mx = fmaxf(mx, __shfl_xor(mx, 16));
      mx = fmaxf(mx, __shfl_xor(mx, 32));
      const float mn = fmaxf(m_i, mx);
      const float alpha = __expf(m_i - mn);
      m_i = mn;
      l_i *= alpha;

      // P = exp(s - m): pack 4 consecutive keys -> one 8B swizzled store per kt
      float lsum = 0.f;
      #pragma unroll
      for (int kt = 0; kt < 4; ++kt) {
        const float p0 = __expf(s4[kt][0] - mn);
        const float p1 = __expf(s4[kt][1] - mn);
        const float p2 = __expf(s4[kt][2] - mn);
        const float p3 = __expf(s4[kt][3] - mn);
        lsum += (p0 + p1) + (p2 + p3);
        uint2 pk;
        pk.x = cvt_pk_bf16(p0, p1);
        pk.y = cvt_pk_bf16(p2, p3);
        *(uint2*)((char*)Pw + r*128 + ((((kt*2 + (qd>>1)) ^ (r&7)) & 7) << 4) + ((qd&1)<<3)) = pk;
      }
      lsum += __shfl_xor(lsum, 16);
      lsum += __shfl_xor(lsum, 32);
      l_i += lsum;
      #pragma unroll
      for (int nt = 0; nt < 4; ++nt)
        #pragma unroll
        for (int rg = 0; rg < 4; ++rg) oacc[nt][rg] *= alpha;

      // ---- O^T += Vt Pt ----
      short8 pf[2];
      #pragma unroll
      for (int ks = 0; ks < 2; ++ks)
        pf[ks] = *(const short8*)&Pw[r*64 + ((((qd + ks*4) ^ (r & 7)) & 7) << 3)];
      __builtin_amdgcn_s_setprio(1);
      #pragma unroll
      for (int nt = 0; nt < 4; ++nt) {
        const int d = nt*16 + r, dg = d >> 3;
        #pragma unroll
        for (int ks = 0; ks < 2; ++ks) {
          short8 vf = *(const short8*)&Vb[d*64 + ((((qd + ks*4) ^ dg) & 7) << 3)];
          oacc[nt] = __builtin_amdgcn_mfma_f32_16x16x32_bf16(vf, pf[ks], oacc[nt], 0, 0, 0);
        }
      }
      __builtin_amdgcn_s_setprio(0);

      // ---- single barrier per tile: publish buf[cur^1] writes; all reads of
      // buf[cur] completed (data consumed by MFMAs above). No vmcnt drain. ----
      asm volatile("s_waitcnt lgkmcnt(0)" ::: "memory");
      __builtin_amdgcn_s_barrier();
    }

    // epilogue: O[q=r][d = nt*16 + qd*4 + rg], lane-local scale, 8B vector stores
    const float invl = 1.0f / l_i;
    bfraw* orow = o + (hb + q0 + w*16 + r) * 1024 + h*64;
    #pragma unroll
    for (int nt = 0; nt < 4; ++nt) {
      uint2 ov;
      ov.x = cvt_pk_bf16(oacc[nt][0]*invl, oacc[nt][1]*invl);
      ov.y = cvt_pk_bf16(oacc[nt][2]*invl, oacc[nt][3]*invl);
      *(uint2*)(orow + nt*16 + qd*4) = ov;
    }
  }
}

// ---------------- host ----------------
extern "C" void kernel_launch(void* const* d_in, const int* in_sizes, int n_in,
                              void* d_out, int out_size, void* d_ws, size_t ws_size,
                              hipStream_t stream) {
  (void)in_sizes; (void)n_in;
  const float* x    = (const float*)d_in[0];
  // d_in[1] = causal mask (int32) -- deterministic tril, handled analytically
  const float* ln1g = (const float*)d_in[2];
  const float* ln1b = (const float*)d_in[3];
  const float* ln2g = (const float*)d_in[4];
  const float* ln2b = (const float*)d_in[5];
  const float* qkvw = (const float*)d_in[6];
  const float* outw = (const float*)d_in[7];
  const float* outb = (const float*)d_in[8];
  const float* fc1w = (const float*)d_in[9];
  const float* fc1b = (const float*)d_in[10];
  const float* fc2w = (const float*)d_in[11];
  const float* fc2b = (const float*)d_in[12];
  float* out = (float*)d_out;   // reference output dtype = float32

  char* ws = (char*)d_ws;
  size_t off = 0;
  auto alloc = [&](size_t bytes) -> void* { void* p = ws + off; off += (bytes + 255) & ~(size_t)255; return p; };
  bfraw* wt_qkv = (bfraw*)alloc(3072ULL*1024*2);
  bfraw* wt_out = (bfraw*)alloc(1024ULL*1024*2);
  bfraw* wt_fc1 = (bfraw*)alloc(4096ULL*1024*2);
  bfraw* wt_fc2 = (bfraw*)alloc(1024ULL*4096*2);
  bfraw* hbuf   = (bfraw*)alloc(8192ULL*1024*2);
  float* x1     = (float*)alloc(8192ULL*1024*4);
  char*  big    = (char*) alloc(8192ULL*3072*2 + 8192ULL*1024*2);
  bfraw* qkv  = (bfraw*)big;
  bfraw* obuf = (bfraw*)(big + 8192ULL*3072*2);
  bfraw* hf   = (bfraw*)big;

  if (off > ws_size) {
    (void)hipMemsetAsync(d_out, 0x7F, (size_t)out_size*4, stream);
    return;
  }

  dim3 tb(64, 16);
  transpose_f32_bf16<<<dim3(48, 16), tb, 0, stream>>>(qkvw, wt_qkv, 1024, 3072);
  transpose_f32_bf16<<<dim3(16, 16), tb, 0, stream>>>(outw, wt_out, 1024, 1024);
  transpose_f32_bf16<<<dim3(64, 16), tb, 0, stream>>>(fc1w, wt_fc1, 1024, 4096);
  transpose_f32_bf16<<<dim3(16, 64), tb, 0, stream>>>(fc2w, wt_fc2, 4096, 1024);

  ln_kernel<<<8192, 256, 0, stream>>>(x, ln1g, ln1b, hbuf);
  gemm_bt<0, bfraw><<<dim3(64, 24), 256, 0, stream>>>(hbuf, wt_qkv, nullptr, nullptr, qkv, 8192, 3072, 1024);
  flash_attn<<<dim3(16, 64), 256, 0, stream>>>(qkv, obuf);
  gemm_bt<1, float><<<dim3(64, 8), 256, 0, stream>>>(obuf, wt_out, outb, x, x1, 8192, 1024, 1024);
  ln_kernel<<<8192, 256, 0, stream>>>(x1, ln2g, ln2b, hbuf);
  gemm_bt<2, bfraw><<<dim3(64, 32), 256, 0, stream>>>(hbuf, wt_fc1, fc1b, nullptr, hf, 8192, 4096, 1024);
  gemm_bt<1, float><<<dim3(64, 8), 256, 0, stream>>>(hf, wt_fc2, fc2b, x1, out, 8192, 1024, 4096);
}

// Round 10
// 580.801 us; speedup vs baseline: 1.1395x; 1.0374x over previous
//
#include <hip/hip_runtime.h>

typedef unsigned short bfraw;
typedef __attribute__((ext_vector_type(8))) short short8;
typedef __attribute__((ext_vector_type(4))) float f32x4;

__device__ __forceinline__ float b2f(bfraw u){ return __uint_as_float(((unsigned int)u)<<16); }
__device__ __forceinline__ bfraw f2b(float f){
  unsigned int u = __float_as_uint(f);
  return (bfraw)((u + 0x7FFFu + ((u>>16)&1u)) >> 16);
}
__device__ __forceinline__ void store_out(float* p, float v){ *p = v; }
__device__ __forceinline__ void store_out(bfraw* p, float v){ *p = f2b(v); }
__device__ __forceinline__ void gload_lds16(const bfraw* g, short* l) {
  __builtin_amdgcn_global_load_lds((const __attribute__((address_space(1))) void*)g,
                                   (__attribute__((address_space(3))) void*)l, 16, 0, 0);
}
// packs bf16(a) into low 16, bf16(b) into high 16 (RNE) — single VALU op
__device__ __forceinline__ unsigned int cvt_pk_bf16(float a, float b) {
  unsigned int r;
  asm("v_cvt_pk_bf16_f32 %0, %1, %2" : "=v"(r) : "v"(a), "v"(b));
  return r;
}

// ---------------- transpose + convert: out[C][R] = bf16(in[R][C]), in fp32 ------
__global__ __launch_bounds__(1024) void transpose_f32_bf16(const float* __restrict__ in,
                                                           bfraw* __restrict__ out,
                                                           int R, int C) {
  __shared__ bfraw tile[64][65];
  const int tx = threadIdx.x, ty = threadIdx.y;
  const int c0 = blockIdx.x*64, r0 = blockIdx.y*64;
  #pragma unroll
  for (int u = 0; u < 4; ++u)
    tile[ty + u*16][tx] = f2b(in[(size_t)(r0 + ty + u*16)*C + c0 + tx]);
  __syncthreads();
  #pragma unroll
  for (int u = 0; u < 4; ++u)
    out[(size_t)(c0 + ty + u*16)*R + r0 + tx] = tile[tx][ty + u*16];
}

// ---------------- layernorm over D=1024: fp32 in, fp32 params, bf16 out ----------
__global__ __launch_bounds__(256) void ln_kernel(const float* __restrict__ x,
                                                 const float* __restrict__ g,
                                                 const float* __restrict__ b,
                                                 bfraw* __restrict__ out) {
  const int row = blockIdx.x, tid = threadIdx.x;
  const f32x4 v = ((const f32x4*)(x + (size_t)row*1024))[tid];
  float s  = v[0]+v[1]+v[2]+v[3];
  float s2 = v[0]*v[0]+v[1]*v[1]+v[2]*v[2]+v[3]*v[3];
  #pragma unroll
  for (int off = 1; off < 64; off <<= 1) { s += __shfl_xor(s, off); s2 += __shfl_xor(s2, off); }
  __shared__ float red[8];
  const int wv = tid>>6, ln_ = tid&63;
  if (ln_ == 0) { red[wv] = s; red[4+wv] = s2; }
  __syncthreads();
  float a  = red[0]+red[1]+red[2]+red[3];
  float a2 = red[4]+red[5]+red[6]+red[7];
  float mean = a*(1.0f/1024.0f);
  float var  = a2*(1.0f/1024.0f) - mean*mean;
  float inv  = rsqrtf(var + 1e-5f);
  const f32x4 gr = ((const f32x4*)g)[tid];
  const f32x4 br = ((const f32x4*)b)[tid];
  ushort4 o4;
  o4.x = f2b((v[0]-mean)*inv*gr[0] + br[0]);
  o4.y = f2b((v[1]-mean)*inv*gr[1] + br[1]);
  o4.z = f2b((v[2]-mean)*inv*gr[2] + br[2]);
  o4.w = f2b((v[3]-mean)*inv*gr[3] + br[3]);
  ((ushort4*)(out + (size_t)row*1024))[tid] = o4;
}

// ---------------- GEMM: C[M,N] = A[M,K] * Bt[N,K]^T (+epilogue) -------------------
// m97 structure, BK=64: same 128^2 tile / 2-barrier loop / high occupancy, but the
// K-tile is 64 so the __syncthreads pair (with its vmcnt drain, the ~20% stall)
// fires half as often. LDS [128][64] shorts per matrix (32 KiB total; 128B rows
// are bank-degenerate so chunk c is stored XOR'd with row&7 — swizzle applied to
// the GLOBAL source at stage time (linear gload_lds dest, rule #21) and to the
// ds_read chunk index. Fragment regs reused across the two ks halves (VGPR flat).
// Accumulation order per acc element identical to BK=32 (k0 then k0+32).
// EPI: 0 = none, 1 = +bias +resid, 2 = +bias +exact GELU
template<int EPI, typename OutT>
__global__ __launch_bounds__(256) void gemm_bt(const bfraw* __restrict__ A,
                                               const bfraw* __restrict__ Bt,
                                               const float* __restrict__ bias,
                                               const float* __restrict__ resid,
                                               OutT* __restrict__ C,
                                               int M, int N, int K) {
  __shared__ __align__(16) short As[128*64];
  __shared__ __align__(16) short Bs[128*64];
  const int tid = threadIdx.x;
  const int wave = tid>>6, lane = tid&63;
  const int wm = wave>>1, wn = wave&1;
  const int q = lane>>4, r = lane&15;
  const int bm = blockIdx.x, bn = blockIdx.y;

  // staging: 1024 x 16B chunks per matrix; thread covers f = i*256+tid, i=0..3.
  // row = f>>3 (= i*32 + tid>>3), stored chunk = f&7; global chunk = (f&7)^(row&7).
  const int srow = tid>>3, sc = tid&7;
  const int gsc = (sc ^ (srow & 7)) * 8;               // pre-swizzled source col (shorts)
  const bfraw* Ag = A  + (size_t)(bm*128 + srow)*K + gsc;
  const bfraw* Bg = Bt + (size_t)(bn*128 + srow)*K + gsc;

  f32x4 acc[4][4];
  #pragma unroll
  for (int mi = 0; mi < 4; ++mi)
    #pragma unroll
    for (int ni = 0; ni < 4; ++ni)
      acc[mi][ni] = (f32x4){0.f, 0.f, 0.f, 0.f};

  const int abase = (wm*64 + r)*64;    // + mi*1024
  const int bbase = (wn*64 + r)*64;    // + ni*1024
  const int r7 = r & 7;

  for (int k0 = 0; k0 < K; k0 += 64) {
    __syncthreads();               // protect LDS readers of previous tile
    #pragma unroll
    for (int i = 0; i < 4; ++i)
      gload_lds16(Ag + (size_t)i*32*K + k0, &As[i*2048 + tid*8]);
    #pragma unroll
    for (int i = 0; i < 4; ++i)
      gload_lds16(Bg + (size_t)i*32*K + k0, &Bs[i*2048 + tid*8]);
    __syncthreads();               // vmcnt drained by compiler before barrier
    #pragma unroll
    for (int ks = 0; ks < 2; ++ks) {
      const int csw = (((ks<<2) | q) ^ r7) << 3;       // swizzled chunk * 8 shorts
      short8 af[4], bfr[4];
      #pragma unroll
      for (int mi = 0; mi < 4; ++mi)
        af[mi] = *(const short8*)&As[abase + mi*1024 + csw];
      #pragma unroll
      for (int ni = 0; ni < 4; ++ni)
        bfr[ni] = *(const short8*)&Bs[bbase + ni*1024 + csw];
      #pragma unroll
      for (int mi = 0; mi < 4; ++mi)
        #pragma unroll
        for (int ni = 0; ni < 4; ++ni)
          acc[mi][ni] = __builtin_amdgcn_mfma_f32_16x16x32_bf16(af[mi], bfr[ni], acc[mi][ni], 0, 0, 0);
    }
  }

  #pragma unroll
  for (int mi = 0; mi < 4; ++mi) {
    #pragma unroll
    for (int ni = 0; ni < 4; ++ni) {
      const int gcol = bn*128 + wn*64 + ni*16 + r;
      float bv = 0.f;
      if constexpr (EPI != 0) bv = bias[gcol];
      #pragma unroll
      for (int rg = 0; rg < 4; ++rg) {
        const int grow = bm*128 + wm*64 + mi*16 + q*4 + rg;
        float val = acc[mi][ni][rg];
        if constexpr (EPI != 0) val += bv;
        if constexpr (EPI == 2) val = 0.5f*val*(1.0f + erff(val*0.70710678118654752f));
        if constexpr (EPI == 1) val += resid[(size_t)grow*N + gcol];
        store_out(&C[(size_t)grow*N + gcol], val);
      }
    }
  }
}

// ---------------- MFMA flash attention (causal), T=2048, HD=64, scale=1/8 ---------
// v5 (unchanged from R9): R1 + double-buffered K/V, one lgkmcnt(0)+s_barrier per
// tile (no vmcnt drain -> t+2 register prefetch stays in flight across barriers).
__global__ __launch_bounds__(256) void flash_attn(const bfraw* __restrict__ qkv,
                                                  bfraw* __restrict__ o) {
  __shared__ __align__(16) short Ksh[2][4096];
  __shared__ __align__(16) short Vts[2][4096];
  __shared__ __align__(16) short Psh[4096];
  const int tid = threadIdx.x;
  const int w = tid >> 6, lane = tid & 63;
  const int r = lane & 15, qd = lane >> 4;
  const int bb = blockIdx.y >> 4, h = blockIdx.y & 15;
  const size_t hb = (size_t)bb * 2048;
  short* Pw = &Psh[w * 1024];
  const int f0 = tid, f1 = tid + 256;
  const int key0 = f0 >> 3, dc0 = (f0 & 7) * 8;
  const int key1 = f1 >> 3, dc1 = (f1 & 7) * 8;

  short8 kpre[2], vpre[2];

  for (int pass = 0; pass < 2; ++pass) {
    const int qt = pass ? (31 - (int)blockIdx.x) : (int)blockIdx.x;
    const int q0 = qt * 64;
    const int ntile = qt + 1;

    short8 qf[2];
    {
      const bfraw* qrow = qkv + (hb + q0 + w*16 + r) * 3072 + h*64;
      qf[0] = *(const short8*)(qrow + qd*8);
      qf[1] = *(const short8*)(qrow + qd*8 + 32);
    }

    f32x4 oacc[4];
    #pragma unroll
    for (int nt = 0; nt < 4; ++nt) oacc[nt] = (f32x4){0.f,0.f,0.f,0.f};
    float m_i = -3.0e38f;
    float l_i = 0.f;

    // ---- prologue: tile 0 -> regs -> buf0; prefetch tile 1 ----
    {
      const bfraw* b0 = qkv + (hb + key0) * 3072 + h*64 + dc0;
      const bfraw* b1 = qkv + (hb + key1) * 3072 + h*64 + dc1;
      kpre[0] = *(const short8*)(b0 + 1024); vpre[0] = *(const short8*)(b0 + 2048);
      kpre[1] = *(const short8*)(b1 + 1024); vpre[1] = *(const short8*)(b1 + 2048);
    }
    __syncthreads();   // previous pass's readers done before restaging buf0
    #pragma unroll
    for (int pz = 0; pz < 2; ++pz) {
      const int key = pz ? key1 : key0, dc = pz ? dc1 : dc0;
      *(short8*)&Ksh[0][key*64 + ((((dc>>3) ^ (key>>3)) & 7) << 3)] = kpre[pz];
      const int kg = key >> 3, k7 = key & 7, dg = dc >> 3;
      #pragma unroll
      for (int i2 = 0; i2 < 8; ++i2)
        Vts[0][(dc + i2)*64 + (((kg ^ dg) & 7) << 3) + k7] = vpre[pz][i2];
    }
    if (ntile > 1) {
      const bfraw* b0 = qkv + (hb + 64 + key0) * 3072 + h*64 + dc0;
      const bfraw* b1 = qkv + (hb + 64 + key1) * 3072 + h*64 + dc1;
      kpre[0] = *(const short8*)(b0 + 1024); vpre[0] = *(const short8*)(b0 + 2048);
      kpre[1] = *(const short8*)(b1 + 1024); vpre[1] = *(const short8*)(b1 + 2048);
    }
    asm volatile("s_waitcnt lgkmcnt(0)" ::: "memory");
    __builtin_amdgcn_s_barrier();

    for (int t = 0; t < ntile; ++t) {
      const int cur = t & 1;
      // ---- stage tile t+1 (prefetched regs) into the other buffer ----
      if (t + 1 < ntile) {
        const int nb = cur ^ 1;
        #pragma unroll
        for (int pz = 0; pz < 2; ++pz) {
          const int key = pz ? key1 : key0, dc = pz ? dc1 : dc0;
          *(short8*)&Ksh[nb][key*64 + ((((dc>>3) ^ (key>>3)) & 7) << 3)] = kpre[pz];
          const int kg = key >> 3, k7 = key & 7, dg = dc >> 3;
          #pragma unroll
          for (int i2 = 0; i2 < 8; ++i2)
            Vts[nb][(dc + i2)*64 + (((kg ^ dg) & 7) << 3) + k7] = vpre[pz][i2];
        }
      }
      // ---- prefetch tile t+2 into regs (in flight across the barrier) ----
      if (t + 2 < ntile) {
        const int j0n = (t + 2) * 64;
        const bfraw* b0 = qkv + (hb + j0n + key0) * 3072 + h*64 + dc0;
        const bfraw* b1 = qkv + (hb + j0n + key1) * 3072 + h*64 + dc1;
        kpre[0] = *(const short8*)(b0 + 1024); vpre[0] = *(const short8*)(b0 + 2048);
        kpre[1] = *(const short8*)(b1 + 1024); vpre[1] = *(const short8*)(b1 + 2048);
      }

      // ---- S^T = K Q^T ----
      const short* Kb = &Ksh[cur][0];
      const short* Vb = &Vts[cur][0];
      f32x4 s4[4];
      __builtin_amdgcn_s_setprio(1);
      #pragma unroll
      for (int kt = 0; kt < 4; ++kt) {
        f32x4 a = (f32x4){0.f,0.f,0.f,0.f};
        const int key = kt*16 + r, kgk = key >> 3;
        #pragma unroll
        for (int ks = 0; ks < 2; ++ks) {
          short8 kf8 = *(const short8*)&Kb[key*64 + ((((qd + ks*4) ^ kgk) & 7) << 3)];
          a = __builtin_amdgcn_mfma_f32_16x16x32_bf16(kf8, qf[ks], a, 0, 0, 0);
        }
        s4[kt] = a;
      }
      __builtin_amdgcn_s_setprio(0);

      // ---- scale + causal mask (diagonal tile only) ----
      const bool diag = (t == qt);
      #pragma unroll
      for (int kt = 0; kt < 4; ++kt)
        #pragma unroll
        for (int rg = 0; rg < 4; ++rg) {
          float v = s4[kt][rg] * 0.125f;
          if (diag && (kt*16 + qd*4 + rg > w*16 + r)) v = -3.0e38f;
          s4[kt][rg] = v;
        }

      // ---- online softmax ----
      float mx = s4[0][0];
      #pragma unroll
      for (int kt = 0; kt < 4; ++kt)
        #pragma unroll
        for (int rg = 0; rg < 4; ++rg) mx = fmaxf(mx, s4[kt][rg]);
      mx = fmaxf(mx, __shfl_xor(mx, 16));
      mx = fmaxf(mx, __shfl_xor(mx, 32));
      const float mn = fmaxf(m_i, mx);
      const float alpha = __expf(m_i - mn);
      m_i = mn;
      l_i *= alpha;

      float lsum = 0.f;
      #pragma unroll
      for (int kt = 0; kt < 4; ++kt) {
        const float p0 = __expf(s4[kt][0] - mn);
        const float p1 = __expf(s4[kt][1] - mn);
        const float p2 = __expf(s4[kt][2] - mn);
        const float p3 = __expf(s4[kt][3] - mn);
        lsum += (p0 + p1) + (p2 + p3);
        uint2 pk;
        pk.x = cvt_pk_bf16(p0, p1);
        pk.y = cvt_pk_bf16(p2, p3);
        *(uint2*)((char*)Pw + r*128 + ((((kt*2 + (qd>>1)) ^ (r&7)) & 7) << 4) + ((qd&1)<<3)) = pk;
      }
      lsum += __shfl_xor(lsum, 16);
      lsum += __shfl_xor(lsum, 32);
      l_i += lsum;
      #pragma unroll
      for (int nt = 0; nt < 4; ++nt)
        #pragma unroll
        for (int rg = 0; rg < 4; ++rg) oacc[nt][rg] *= alpha;

      // ---- O^T += Vt Pt ----
      short8 pf[2];
      #pragma unroll
      for (int ks = 0; ks < 2; ++ks)
        pf[ks] = *(const short8*)&Pw[r*64 + ((((qd + ks*4) ^ (r & 7)) & 7) << 3)];
      __builtin_amdgcn_s_setprio(1);
      #pragma unroll
      for (int nt = 0; nt < 4; ++nt) {
        const int d = nt*16 + r, dg = d >> 3;
        #pragma unroll
        for (int ks = 0; ks < 2; ++ks) {
          short8 vf = *(const short8*)&Vb[d*64 + ((((qd + ks*4) ^ dg) & 7) << 3)];
          oacc[nt] = __builtin_amdgcn_mfma_f32_16x16x32_bf16(vf, pf[ks], oacc[nt], 0, 0, 0);
        }
      }
      __builtin_amdgcn_s_setprio(0);

      // ---- single barrier per tile (no vmcnt drain) ----
      asm volatile("s_waitcnt lgkmcnt(0)" ::: "memory");
      __builtin_amdgcn_s_barrier();
    }

    // epilogue
    const float invl = 1.0f / l_i;
    bfraw* orow = o + (hb + q0 + w*16 + r) * 1024 + h*64;
    #pragma unroll
    for (int nt = 0; nt < 4; ++nt) {
      uint2 ov;
      ov.x = cvt_pk_bf16(oacc[nt][0]*invl, oacc[nt][1]*invl);
      ov.y = cvt_pk_bf16(oacc[nt][2]*invl, oacc[nt][3]*invl);
      *(uint2*)(orow + nt*16 + qd*4) = ov;
    }
  }
}

// ---------------- host ----------------
extern "C" void kernel_launch(void* const* d_in, const int* in_sizes, int n_in,
                              void* d_out, int out_size, void* d_ws, size_t ws_size,
                              hipStream_t stream) {
  (void)in_sizes; (void)n_in;
  const float* x    = (const float*)d_in[0];
  // d_in[1] = causal mask (int32) -- deterministic tril, handled analytically
  const float* ln1g = (const float*)d_in[2];
  const float* ln1b = (const float*)d_in[3];
  const float* ln2g = (const float*)d_in[4];
  const float* ln2b = (const float*)d_in[5];
  const float* qkvw = (const float*)d_in[6];
  const float* outw = (const float*)d_in[7];
  const float* outb = (const float*)d_in[8];
  const float* fc1w = (const float*)d_in[9];
  const float* fc1b = (const float*)d_in[10];
  const float* fc2w = (const float*)d_in[11];
  const float* fc2b = (const float*)d_in[12];
  float* out = (float*)d_out;   // reference output dtype = float32

  char* ws = (char*)d_ws;
  size_t off = 0;
  auto alloc = [&](size_t bytes) -> void* { void* p = ws + off; off += (bytes + 255) & ~(size_t)255; return p; };
  bfraw* wt_qkv = (bfraw*)alloc(3072ULL*1024*2);
  bfraw* wt_out = (bfraw*)alloc(1024ULL*1024*2);
  bfraw* wt_fc1 = (bfraw*)alloc(4096ULL*1024*2);
  bfraw* wt_fc2 = (bfraw*)alloc(1024ULL*4096*2);
  bfraw* hbuf   = (bfraw*)alloc(8192ULL*1024*2);
  float* x1     = (float*)alloc(8192ULL*1024*4);
  char*  big    = (char*) alloc(8192ULL*3072*2 + 8192ULL*1024*2);
  bfraw* qkv  = (bfraw*)big;
  bfraw* obuf = (bfraw*)(big + 8192ULL*3072*2);
  bfraw* hf   = (bfraw*)big;

  if (off > ws_size) {
    (void)hipMemsetAsync(d_out, 0x7F, (size_t)out_size*4, stream);
    return;
  }

  dim3 tb(64, 16);
  transpose_f32_bf16<<<dim3(48, 16), tb, 0, stream>>>(qkvw, wt_qkv, 1024, 3072);
  transpose_f32_bf16<<<dim3(16, 16), tb, 0, stream>>>(outw, wt_out, 1024, 1024);
  transpose_f32_bf16<<<dim3(64, 16), tb, 0, stream>>>(fc1w, wt_fc1, 1024, 4096);
  transpose_f32_bf16<<<dim3(16, 64), tb, 0, stream>>>(fc2w, wt_fc2, 4096, 1024);

  ln_kernel<<<8192, 256, 0, stream>>>(x, ln1g, ln1b, hbuf);
  gemm_bt<0, bfraw><<<dim3(64, 24), 256, 0, stream>>>(hbuf, wt_qkv, nullptr, nullptr, qkv, 8192, 3072, 1024);
  flash_attn<<<dim3(16, 64), 256, 0, stream>>>(qkv, obuf);
  gemm_bt<1, float><<<dim3(64, 8), 256, 0, stream>>>(obuf, wt_out, outb, x, x1, 8192, 1024, 1024);
  ln_kernel<<<8192, 256, 0, stream>>>(x1, ln2g, ln2b, hbuf);
  gemm_bt<2, bfraw><<<dim3(64, 32), 256, 0, stream>>>(hbuf, wt_fc1, fc1b, nullptr, hf, 8192, 4096, 1024);
  gemm_bt<1, float><<<dim3(64, 8), 256, 0, stream>>>(hf, wt_fc2, fc2b, x1, out, 8192, 1024, 4096);
}

// Round 11
// 567.691 us; speedup vs baseline: 1.1658x; 1.0231x over previous
//
#include <hip/hip_runtime.h>

typedef unsigned short bfraw;
typedef __attribute__((ext_vector_type(8))) short short8;
typedef __attribute__((ext_vector_type(4))) float f32x4;

__device__ __forceinline__ float b2f(bfraw u){ return __uint_as_float(((unsigned int)u)<<16); }
__device__ __forceinline__ bfraw f2b(float f){
  unsigned int u = __float_as_uint(f);
  return (bfraw)((u + 0x7FFFu + ((u>>16)&1u)) >> 16);
}
__device__ __forceinline__ void store_out(float* p, float v){ *p = v; }
__device__ __forceinline__ void store_out(bfraw* p, float v){ *p = f2b(v); }
__device__ __forceinline__ void gload_lds16(const bfraw* g, short* l) {
  __builtin_amdgcn_global_load_lds((const __attribute__((address_space(1))) void*)g,
                                   (__attribute__((address_space(3))) void*)l, 16, 0, 0);
}
// packs bf16(a) into low 16, bf16(b) into high 16 (RNE) — single VALU op
__device__ __forceinline__ unsigned int cvt_pk_bf16(float a, float b) {
  unsigned int r;
  asm("v_cvt_pk_bf16_f32 %0, %1, %2" : "=v"(r) : "v"(a), "v"(b));
  return r;
}

// ---------------- transpose + convert: out[C][R] = bf16(in[R][C]), in fp32 ------
__global__ __launch_bounds__(1024) void transpose_f32_bf16(const float* __restrict__ in,
                                                           bfraw* __restrict__ out,
                                                           int R, int C) {
  __shared__ bfraw tile[64][65];
  const int tx = threadIdx.x, ty = threadIdx.y;
  const int c0 = blockIdx.x*64, r0 = blockIdx.y*64;
  #pragma unroll
  for (int u = 0; u < 4; ++u)
    tile[ty + u*16][tx] = f2b(in[(size_t)(r0 + ty + u*16)*C + c0 + tx]);
  __syncthreads();
  #pragma unroll
  for (int u = 0; u < 4; ++u)
    out[(size_t)(c0 + ty + u*16)*R + r0 + tx] = tile[tx][ty + u*16];
}

// ---------------- layernorm over D=1024: fp32 in, fp32 params, bf16 out ----------
__global__ __launch_bounds__(256) void ln_kernel(const float* __restrict__ x,
                                                 const float* __restrict__ g,
                                                 const float* __restrict__ b,
                                                 bfraw* __restrict__ out) {
  const int row = blockIdx.x, tid = threadIdx.x;
  const f32x4 v = ((const f32x4*)(x + (size_t)row*1024))[tid];
  float s  = v[0]+v[1]+v[2]+v[3];
  float s2 = v[0]*v[0]+v[1]*v[1]+v[2]*v[2]+v[3]*v[3];
  #pragma unroll
  for (int off = 1; off < 64; off <<= 1) { s += __shfl_xor(s, off); s2 += __shfl_xor(s2, off); }
  __shared__ float red[8];
  const int wv = tid>>6, ln_ = tid&63;
  if (ln_ == 0) { red[wv] = s; red[4+wv] = s2; }
  __syncthreads();
  float a  = red[0]+red[1]+red[2]+red[3];
  float a2 = red[4]+red[5]+red[6]+red[7];
  float mean = a*(1.0f/1024.0f);
  float var  = a2*(1.0f/1024.0f) - mean*mean;
  float inv  = rsqrtf(var + 1e-5f);
  const f32x4 gr = ((const f32x4*)g)[tid];
  const f32x4 br = ((const f32x4*)b)[tid];
  ushort4 o4;
  o4.x = f2b((v[0]-mean)*inv*gr[0] + br[0]);
  o4.y = f2b((v[1]-mean)*inv*gr[1] + br[1]);
  o4.z = f2b((v[2]-mean)*inv*gr[2] + br[2]);
  o4.w = f2b((v[3]-mean)*inv*gr[3] + br[3]);
  ((ushort4*)(out + (size_t)row*1024))[tid] = o4;
}

// ---------------- GEMM: C[M,N] = A[M,K] * Bt[N,K]^T (+epilogue) -------------------
// m97 structure, BK=64 (R10-proven: halves the __syncthreads/vmcnt-drain frequency
// vs BK=32 at unchanged occupancy; fc1 dropped below the attn dispatch in R10).
// LDS [128][64] shorts per matrix; chunk c stored XOR'd with row&7 — swizzle
// applied to the GLOBAL source at stage time (linear gload_lds dest, rule #21)
// and to the ds_read chunk index. Accumulation order identical to BK=32.
// EPI: 0 = none, 1 = +bias +resid, 2 = +bias +exact GELU
template<int EPI, typename OutT>
__global__ __launch_bounds__(256) void gemm_bt(const bfraw* __restrict__ A,
                                               const bfraw* __restrict__ Bt,
                                               const float* __restrict__ bias,
                                               const float* __restrict__ resid,
                                               OutT* __restrict__ C,
                                               int M, int N, int K) {
  __shared__ __align__(16) short As[128*64];
  __shared__ __align__(16) short Bs[128*64];
  const int tid = threadIdx.x;
  const int wave = tid>>6, lane = tid&63;
  const int wm = wave>>1, wn = wave&1;
  const int q = lane>>4, r = lane&15;
  const int bm = blockIdx.x, bn = blockIdx.y;

  // staging: 1024 x 16B chunks per matrix; thread covers f = i*256+tid, i=0..3.
  // row = f>>3 (= i*32 + tid>>3), stored chunk = f&7; global chunk = (f&7)^(row&7).
  const int srow = tid>>3, sc = tid&7;
  const int gsc = (sc ^ (srow & 7)) * 8;               // pre-swizzled source col (shorts)
  const bfraw* Ag = A  + (size_t)(bm*128 + srow)*K + gsc;
  const bfraw* Bg = Bt + (size_t)(bn*128 + srow)*K + gsc;

  f32x4 acc[4][4];
  #pragma unroll
  for (int mi = 0; mi < 4; ++mi)
    #pragma unroll
    for (int ni = 0; ni < 4; ++ni)
      acc[mi][ni] = (f32x4){0.f, 0.f, 0.f, 0.f};

  const int abase = (wm*64 + r)*64;    // + mi*1024
  const int bbase = (wn*64 + r)*64;    // + ni*1024
  const int r7 = r & 7;

  for (int k0 = 0; k0 < K; k0 += 64) {
    __syncthreads();               // protect LDS readers of previous tile
    #pragma unroll
    for (int i = 0; i < 4; ++i)
      gload_lds16(Ag + (size_t)i*32*K + k0, &As[i*2048 + tid*8]);
    #pragma unroll
    for (int i = 0; i < 4; ++i)
      gload_lds16(Bg + (size_t)i*32*K + k0, &Bs[i*2048 + tid*8]);
    __syncthreads();               // vmcnt drained by compiler before barrier
    #pragma unroll
    for (int ks = 0; ks < 2; ++ks) {
      const int csw = (((ks<<2) | q) ^ r7) << 3;       // swizzled chunk * 8 shorts
      short8 af[4], bfr[4];
      #pragma unroll
      for (int mi = 0; mi < 4; ++mi)
        af[mi] = *(const short8*)&As[abase + mi*1024 + csw];
      #pragma unroll
      for (int ni = 0; ni < 4; ++ni)
        bfr[ni] = *(const short8*)&Bs[bbase + ni*1024 + csw];
      #pragma unroll
      for (int mi = 0; mi < 4; ++mi)
        #pragma unroll
        for (int ni = 0; ni < 4; ++ni)
          acc[mi][ni] = __builtin_amdgcn_mfma_f32_16x16x32_bf16(af[mi], bfr[ni], acc[mi][ni], 0, 0, 0);
    }
  }

  #pragma unroll
  for (int mi = 0; mi < 4; ++mi) {
    #pragma unroll
    for (int ni = 0; ni < 4; ++ni) {
      const int gcol = bn*128 + wn*64 + ni*16 + r;
      float bv = 0.f;
      if constexpr (EPI != 0) bv = bias[gcol];
      #pragma unroll
      for (int rg = 0; rg < 4; ++rg) {
        const int grow = bm*128 + wm*64 + mi*16 + q*4 + rg;
        float val = acc[mi][ni][rg];
        if constexpr (EPI != 0) val += bv;
        if constexpr (EPI == 2) val = 0.5f*val*(1.0f + erff(val*0.70710678118654752f));
        if constexpr (EPI == 1) val += resid[(size_t)grow*N + gcol];
        store_out(&C[(size_t)grow*N + gcol], val);
      }
    }
  }
}

// ---------------- MFMA flash attention (causal), T=2048, HD=64, scale=1/8 ---------
// Reverted byte-identical to R1 v2 (130.4 us, VGPR 68, occ 27%): single-buffer
// KVBLK=64, two __syncthreads per tile, t+1 register prefetch. The v5
// double-buffer (R10) raised VGPR to 84 / cut occupancy to 23% and regressed to
// 147 us — in this latency-bound kernel, occupancy beats barrier count.
__global__ __launch_bounds__(256) void flash_attn(const bfraw* __restrict__ qkv,
                                                  bfraw* __restrict__ o) {
  __shared__ __align__(16) short Ksh[4096];
  __shared__ __align__(16) short Vts[4096];
  __shared__ __align__(16) short Psh[4096];
  const int tid = threadIdx.x;
  const int w = tid >> 6, lane = tid & 63;
  const int r = lane & 15, qd = lane >> 4;
  const int bb = blockIdx.y >> 4, h = blockIdx.y & 15;
  const size_t hb = (size_t)bb * 2048;
  short* Pw = &Psh[w * 1024];
  const int f0 = tid, f1 = tid + 256;
  const int key0 = f0 >> 3, dc0 = (f0 & 7) * 8;
  const int key1 = f1 >> 3, dc1 = (f1 & 7) * 8;

  for (int pass = 0; pass < 2; ++pass) {
    const int qt = pass ? (31 - (int)blockIdx.x) : (int)blockIdx.x;
    const int q0 = qt * 64;
    const int ntile = qt + 1;

    // Q fragments: lane holds Q[q=r][k=qd*8+ks*32+j] (B operand)
    short8 qf[2];
    {
      const bfraw* qrow = qkv + (hb + q0 + w*16 + r) * 3072 + h*64;
      qf[0] = *(const short8*)(qrow + qd*8);
      qf[1] = *(const short8*)(qrow + qd*8 + 32);
    }

    f32x4 oacc[4];
    #pragma unroll
    for (int nt = 0; nt < 4; ++nt) oacc[nt] = (f32x4){0.f,0.f,0.f,0.f};
    float m_i = -3.0e38f;
    float l_i = 0.f;

    // prefetch tile 0
    short8 kpre[2], vpre[2];
    {
      const bfraw* b0 = qkv + (hb + key0) * 3072 + h*64 + dc0;
      const bfraw* b1 = qkv + (hb + key1) * 3072 + h*64 + dc1;
      kpre[0] = *(const short8*)(b0 + 1024); vpre[0] = *(const short8*)(b0 + 2048);
      kpre[1] = *(const short8*)(b1 + 1024); vpre[1] = *(const short8*)(b1 + 2048);
    }

    for (int t = 0; t < ntile; ++t) {
      __syncthreads();   // protect LDS vs previous tile / previous pass
      // ---- write prefetched K [key][dim] and Vt [dim][key] (swizzled) ----
      #pragma unroll
      for (int pz = 0; pz < 2; ++pz) {
        const int key = pz ? key1 : key0, dc = pz ? dc1 : dc0;
        *(short8*)&Ksh[key*64 + ((((dc>>3) ^ (key>>3)) & 7) << 3)] = kpre[pz];
        const int kg = key >> 3, k7 = key & 7, dg = dc >> 3;
        #pragma unroll
        for (int i2 = 0; i2 < 8; ++i2)
          Vts[(dc + i2)*64 + (((kg ^ dg) & 7) << 3) + k7] = vpre[pz][i2];
      }
      __syncthreads();
      // ---- prefetch next tile into regs (overlaps compute below) ----
      if (t + 1 < ntile) {
        const int j0n = (t + 1) * 64;
        const bfraw* b0 = qkv + (hb + j0n + key0) * 3072 + h*64 + dc0;
        const bfraw* b1 = qkv + (hb + j0n + key1) * 3072 + h*64 + dc1;
        kpre[0] = *(const short8*)(b0 + 1024); vpre[0] = *(const short8*)(b0 + 2048);
        kpre[1] = *(const short8*)(b1 + 1024); vpre[1] = *(const short8*)(b1 + 2048);
      }

      // ---- S^T = K Q^T : col = lane&15 = q-row, row = kt*16 + qd*4 + rg = key ----
      f32x4 s4[4];
      __builtin_amdgcn_s_setprio(1);
      #pragma unroll
      for (int kt = 0; kt < 4; ++kt) {
        f32x4 a = (f32x4){0.f,0.f,0.f,0.f};
        const int key = kt*16 + r, kgk = key >> 3;
        #pragma unroll
        for (int ks = 0; ks < 2; ++ks) {
          short8 kf8 = *(const short8*)&Ksh[key*64 + ((((qd + ks*4) ^ kgk) & 7) << 3)];
          a = __builtin_amdgcn_mfma_f32_16x16x32_bf16(kf8, qf[ks], a, 0, 0, 0);
        }
        s4[kt] = a;
      }
      __builtin_amdgcn_s_setprio(0);

      // ---- scale + causal mask (diagonal tile only) ----
      const bool diag = (t == qt);
      #pragma unroll
      for (int kt = 0; kt < 4; ++kt)
        #pragma unroll
        for (int rg = 0; rg < 4; ++rg) {
          float v = s4[kt][rg] * 0.125f;
          if (diag && (kt*16 + qd*4 + rg > w*16 + r)) v = -3.0e38f;
          s4[kt][rg] = v;
        }

      // ---- online softmax: lane owns row r; its 16 keys + xor(16,32) reduce ----
      float mx = s4[0][0];
      #pragma unroll
      for (int kt = 0; kt < 4; ++kt)
        #pragma unroll
        for (int rg = 0; rg < 4; ++rg) mx = fmaxf(mx, s4[kt][rg]);
      mx = fmaxf(mx, __shfl_xor(mx, 16));
      mx = fmaxf(mx, __shfl_xor(mx, 32));
      const float mn = fmaxf(m_i, mx);
      const float alpha = __expf(m_i - mn);
      m_i = mn;
      l_i *= alpha;

      // P = exp(s - m): pack 4 consecutive keys -> one 8B swizzled store per kt
      float lsum = 0.f;
      #pragma unroll
      for (int kt = 0; kt < 4; ++kt) {
        const float p0 = __expf(s4[kt][0] - mn);
        const float p1 = __expf(s4[kt][1] - mn);
        const float p2 = __expf(s4[kt][2] - mn);
        const float p3 = __expf(s4[kt][3] - mn);
        lsum += (p0 + p1) + (p2 + p3);
        uint2 pk;
        pk.x = cvt_pk_bf16(p0, p1);
        pk.y = cvt_pk_bf16(p2, p3);
        *(uint2*)((char*)Pw + r*128 + ((((kt*2 + (qd>>1)) ^ (r&7)) & 7) << 4) + ((qd&1)<<3)) = pk;
      }
      lsum += __shfl_xor(lsum, 16);
      lsum += __shfl_xor(lsum, 32);
      l_i += lsum;
      #pragma unroll
      for (int nt = 0; nt < 4; ++nt)
        #pragma unroll
        for (int rg = 0; rg < 4; ++rg) oacc[nt][rg] *= alpha;

      // ---- O^T += Vt Pt ----
      short8 pf[2];
      #pragma unroll
      for (int ks = 0; ks < 2; ++ks)
        pf[ks] = *(const short8*)&Pw[r*64 + ((((qd + ks*4) ^ (r & 7)) & 7) << 3)];
      __builtin_amdgcn_s_setprio(1);
      #pragma unroll
      for (int nt = 0; nt < 4; ++nt) {
        const int d = nt*16 + r, dg = d >> 3;
        #pragma unroll
        for (int ks = 0; ks < 2; ++ks) {
          short8 vf = *(const short8*)&Vts[d*64 + ((((qd + ks*4) ^ dg) & 7) << 3)];
          oacc[nt] = __builtin_amdgcn_mfma_f32_16x16x32_bf16(vf, pf[ks], oacc[nt], 0, 0, 0);
        }
      }
      __builtin_amdgcn_s_setprio(0);
    }

    // epilogue: O[q=r][d = nt*16 + qd*4 + rg], lane-local scale, 8B vector stores
    const float invl = 1.0f / l_i;
    bfraw* orow = o + (hb + q0 + w*16 + r) * 1024 + h*64;
    #pragma unroll
    for (int nt = 0; nt < 4; ++nt) {
      uint2 ov;
      ov.x = cvt_pk_bf16(oacc[nt][0]*invl, oacc[nt][1]*invl);
      ov.y = cvt_pk_bf16(oacc[nt][2]*invl, oacc[nt][3]*invl);
      *(uint2*)(orow + nt*16 + qd*4) = ov;
    }
  }
}

// ---------------- host ----------------
extern "C" void kernel_launch(void* const* d_in, const int* in_sizes, int n_in,
                              void* d_out, int out_size, void* d_ws, size_t ws_size,
                              hipStream_t stream) {
  (void)in_sizes; (void)n_in;
  const float* x    = (const float*)d_in[0];
  // d_in[1] = causal mask (int32) -- deterministic tril, handled analytically
  const float* ln1g = (const float*)d_in[2];
  const float* ln1b = (const float*)d_in[3];
  const float* ln2g = (const float*)d_in[4];
  const float* ln2b = (const float*)d_in[5];
  const float* qkvw = (const float*)d_in[6];
  const float* outw = (const float*)d_in[7];
  const float* outb = (const float*)d_in[8];
  const float* fc1w = (const float*)d_in[9];
  const float* fc1b = (const float*)d_in[10];
  const float* fc2w = (const float*)d_in[11];
  const float* fc2b = (const float*)d_in[12];
  float* out = (float*)d_out;   // reference output dtype = float32

  char* ws = (char*)d_ws;
  size_t off = 0;
  auto alloc = [&](size_t bytes) -> void* { void* p = ws + off; off += (bytes + 255) & ~(size_t)255; return p; };
  bfraw* wt_qkv = (bfraw*)alloc(3072ULL*1024*2);
  bfraw* wt_out = (bfraw*)alloc(1024ULL*1024*2);
  bfraw* wt_fc1 = (bfraw*)alloc(4096ULL*1024*2);
  bfraw* wt_fc2 = (bfraw*)alloc(1024ULL*4096*2);
  bfraw* hbuf   = (bfraw*)alloc(8192ULL*1024*2);
  float* x1     = (float*)alloc(8192ULL*1024*4);
  char*  big    = (char*) alloc(8192ULL*3072*2 + 8192ULL*1024*2);
  bfraw* qkv  = (bfraw*)big;
  bfraw* obuf = (bfraw*)(big + 8192ULL*3072*2);
  bfraw* hf   = (bfraw*)big;

  if (off > ws_size) {
    (void)hipMemsetAsync(d_out, 0x7F, (size_t)out_size*4, stream);
    return;
  }

  dim3 tb(64, 16);
  transpose_f32_bf16<<<dim3(48, 16), tb, 0, stream>>>(qkvw, wt_qkv, 1024, 3072);
  transpose_f32_bf16<<<dim3(16, 16), tb, 0, stream>>>(outw, wt_out, 1024, 1024);
  transpose_f32_bf16<<<dim3(64, 16), tb, 0, stream>>>(fc1w, wt_fc1, 1024, 4096);
  transpose_f32_bf16<<<dim3(16, 64), tb, 0, stream>>>(fc2w, wt_fc2, 4096, 1024);

  ln_kernel<<<8192, 256, 0, stream>>>(x, ln1g, ln1b, hbuf);
  gemm_bt<0, bfraw><<<dim3(64, 24), 256, 0, stream>>>(hbuf, wt_qkv, nullptr, nullptr, qkv, 8192, 3072, 1024);
  flash_attn<<<dim3(16, 64), 256, 0, stream>>>(qkv, obuf);
  gemm_bt<1, float><<<dim3(64, 8), 256, 0, stream>>>(obuf, wt_out, outb, x, x1, 8192, 1024, 1024);
  ln_kernel<<<8192, 256, 0, stream>>>(x1, ln2g, ln2b, hbuf);
  gemm_bt<2, bfraw><<<dim3(64, 32), 256, 0, stream>>>(hbuf, wt_fc1, fc1b, nullptr, hf, 8192, 4096, 1024);
  gemm_bt<1, float><<<dim3(64, 8), 256, 0, stream>>>(hf, wt_fc2, fc2b, x1, out, 8192, 1024, 4096);
}